// Round 12
// baseline (406.391 us; speedup 1.0000x reference)
//
#include <hip/hip_runtime.h>
#include <hip/hip_bf16.h>

#define B_  4
#define C_  256
#define C2_ 128
#define N_  4096
#define LOG2E 1.4426950408889634f

typedef unsigned short u16;
typedef __attribute__((ext_vector_type(8))) short bf16x8;  // 8 bf16 in 4 VGPRs
typedef __attribute__((ext_vector_type(4))) float f32x4;

static __device__ __forceinline__ u16 f2bf(float f) {
    return __builtin_bit_cast(u16, __float2bfloat16(f));
}
static __device__ __forceinline__ float bf2f(u16 u) {
    return __bfloat162float(__builtin_bit_cast(__hip_bfloat16, u));
}
static __device__ __forceinline__ bf16x8 cvt8(const float* p) {
    u16 t[8];
#pragma unroll
    for (int j = 0; j < 8; ++j) t[j] = f2bf(p[j]);
    return *(const bf16x8*)t;
}

// Software grid barrier. Counters zeroed by hipMemsetAsync before launch.
// All blocks are co-resident by construction (grid <= 2 blocks/CU x 256 CU;
// LDS 54272 B and VGPR<=128 both admit 2 blocks/CU). Device-scope atomics
// cross XCDs; __threadfence() makes prior global writes visible (G16).
static __device__ __forceinline__ void grid_barrier(unsigned* cnt, unsigned target) {
    __syncthreads();
    if (threadIdx.x == 0) {
        __threadfence();
        __hip_atomic_fetch_add(cnt, 1u, __ATOMIC_ACQ_REL, __HIP_MEMORY_SCOPE_AGENT);
        while (__hip_atomic_load(cnt, __ATOMIC_ACQUIRE, __HIP_MEMORY_SCOPE_AGENT) < target) {
            __builtin_amdgcn_s_sleep(8);
        }
    }
    __syncthreads();
}

// ---------------------------------------------------------------------------
// Single fused kernel, 3 phases separated by software grid barriers:
//  A: fused x-transpose + 3-way MFMA projection (r10-proven projx body)
//  B: flash attention, BM=128, split-K S (r7-proven 56us body, bf16 partials)
//  C: split-K combine + out-projection + residual (r8-proven body)
// grid = 128*S (S=4 -> 512 = 2 blocks/CU). Launch gaps are the target.
// ---------------------------------------------------------------------------
__global__ __launch_bounds__(256, 2) void fused_kernel(
    const float* __restrict__ x,
    const float* __restrict__ wt, const float* __restrict__ wp,
    const float* __restrict__ wg,
    const float* __restrict__ b_theta, const float* __restrict__ b_phi,
    const float* __restrict__ b_g,
    const float* __restrict__ w_out, const float* __restrict__ b_out,
    float* __restrict__ y,
    u16* __restrict__ Q, u16* __restrict__ K, u16* __restrict__ V,
    u16* __restrict__ AO, u16* __restrict__ Opb, float* __restrict__ lsum,
    unsigned* __restrict__ bar, int nsplit) {
    // 54272 B static LDS, overlaid per phase
    __shared__ __align__(16) u16 smA[64][136];     // 17408 B
    __shared__ __align__(16) u16 smB[128][72];     // 18432 B
    __shared__ __align__(16) u16 smC[4][32][72];   // 18432 B

    int tid  = threadIdx.x;
    int wave = tid >> 6, lane = tid & 63, quad = (lane >> 4) & 3, l16 = lane & 15;
    const unsigned target = gridDim.x;

    // ===================== Phase A: QKV projections =====================
    {
        u16* XTs = (u16*)smA;                       // [32][264] = 16896 B
        u16 (*Vt)[40] = (u16(*)[40])smB;            // [128][40] = 10240 B
        int mgrp = wave >> 1, chalf = wave & 1;
        const float* wms[3]    = { wt, wp, wg };
        const float* biases[3] = { b_theta, b_phi, b_g };

        for (int wb = blockIdx.x; wb < B_ * (N_ / 32); wb += gridDim.x) {
            int b  = wb / (N_ / 32);
            int n0 = (wb % (N_ / 32)) * 32;

            // stage + transpose x tile [256 c][32 n] fp32 -> XTs bf16
#pragma unroll
            for (int it = 0; it < 4; ++it) {
                int idx = it * 256 + tid;
                int q = idx & 7, p = idx >> 3;
                const float* r0 = x + ((size_t)b * C_ + 2 * p) * N_ + n0 + 4 * q;
                float4 v0 = *(const float4*)r0;
                float4 v1 = *(const float4*)(r0 + N_);
                const float* f0 = (const float*)&v0;
                const float* f1 = (const float*)&v1;
#pragma unroll
                for (int j = 0; j < 4; ++j) {
                    unsigned pk = (unsigned)f2bf(f0[j]) | ((unsigned)f2bf(f1[j]) << 16);
                    *(unsigned*)&XTs[(size_t)(4 * q + j) * 264 + 2 * p] = pk;
                }
            }
            __syncthreads();

            bf16x8 af[8];
#pragma unroll
            for (int ks = 0; ks < 8; ++ks)
                af[ks] = *(const bf16x8*)
                    &XTs[(size_t)(mgrp * 16 + l16) * 264 + ks * 32 + quad * 8];
            __syncthreads();   // XTs consumed; Vt (smB) free

#pragma unroll
            for (int mat = 0; mat < 3; ++mat) {
                const float* wm = wms[mat];
                const float* bias = biases[mat];
                f32x4 acc[4];
#pragma unroll
                for (int i = 0; i < 4; ++i) acc[i] = (f32x4){0.f, 0.f, 0.f, 0.f};
#pragma unroll
                for (int ct = 0; ct < 4; ++ct) {
                    int ce = chalf * 4 + ct;
                    const float* wr = wm + (size_t)(ce * 16 + l16) * C_ + quad * 8;
#pragma unroll
                    for (int ks = 0; ks < 8; ++ks) {
                        float w8[8];
                        *(float4*)&w8[0] = *(const float4*)(wr + ks * 32);
                        *(float4*)&w8[4] = *(const float4*)(wr + ks * 32 + 4);
                        bf16x8 bf = cvt8(w8);
                        acc[ct] = __builtin_amdgcn_mfma_f32_16x16x32_bf16(
                            af[ks], bf, acc[ct], 0, 0, 0);
                    }
                }
                if (mat < 2) {
                    u16* dst = mat == 0 ? Q : K;
                    float sc = mat == 0 ? LOG2E : 1.0f;
#pragma unroll
                    for (int ct = 0; ct < 4; ++ct) {
                        int c2 = (chalf * 4 + ct) * 16 + l16;
                        float bb = bias[c2];
#pragma unroll
                        for (int r = 0; r < 4; ++r) {
                            int n = n0 + mgrp * 16 + quad * 4 + r;
                            dst[((size_t)b * N_ + n) * C2_ + c2] =
                                f2bf((acc[ct][r] + bb) * sc);
                        }
                    }
                } else {
#pragma unroll
                    for (int ct = 0; ct < 4; ++ct) {
                        int c2 = (chalf * 4 + ct) * 16 + l16;
                        float bb = bias[c2];
#pragma unroll
                        for (int r = 0; r < 4; ++r)
                            Vt[c2][mgrp * 16 + quad * 4 + r] = f2bf(acc[ct][r] + bb);
                    }
                }
            }
            __syncthreads();
            {   // cooperative V[b][c2][n] write: 128 rows x 32 n
                int row = tid >> 1, col16 = (tid & 1) * 16;
                uint4 a0 = *(const uint4*)&Vt[row][col16];
                uint4 a1 = *(const uint4*)&Vt[row][col16 + 8];
                u16* vp = V + ((size_t)b * C2_ + row) * N_ + n0 + col16;
                *(uint4*)vp = a0;
                *(uint4*)(vp + 8) = a1;
            }
            __syncthreads();
        }
    }
    grid_barrier(&bar[0], target);

    // ===================== Phase B: flash attention =====================
    {
        const int BM = 128, BN = 64, D = C2_;
        const int per = B_ * (N_ / BM);      // 128
        int s  = blockIdx.x / per;
        int r0 = blockIdx.x % per;
        int b  = r0 / (N_ / BM);
        int m0 = (r0 % (N_ / BM)) * BM;

        u16 (*Ks)[136] = (u16(*)[136])smA;
        u16 (*Vs)[72]  = (u16(*)[72])smB;
        u16* Ps = &smC[wave][0][0];

        bf16x8 qf[2][4];
#pragma unroll
        for (int ms = 0; ms < 2; ++ms) {
            const u16* qp = Q + ((size_t)b * N_ + m0 + wave * 32 + ms * 16 + l16) * D;
#pragma unroll
            for (int kk = 0; kk < 4; ++kk)
                qf[ms][kk] = *(const bf16x8*)(qp + kk * 32 + quad * 8);
        }

        float l_r[2][4] = {{0.f, 0.f, 0.f, 0.f}, {0.f, 0.f, 0.f, 0.f}};
        f32x4 o_acc[2][8];
#pragma unroll
        for (int ms = 0; ms < 2; ++ms)
#pragma unroll
            for (int i = 0; i < 8; ++i) o_acc[ms][i] = (f32x4){0.f, 0.f, 0.f, 0.f};

        const int chunk = N_ / nsplit;       // S in {1,2,4}: even
        const int nt0 = s * chunk, nt1 = nt0 + chunk;

        for (int nt = nt0; nt < nt1; nt += BN) {
            const u16* kp = K + ((size_t)b * N_ + nt) * D;
#pragma unroll
            for (int it = 0; it < 4; ++it) {
                int idx = it * 256 + tid;
                int row = idx >> 4, col = (idx & 15) * 8;
                *(uint4*)&Ks[row][col] = *(const uint4*)(kp + row * D + col);
            }
#pragma unroll
            for (int it = 0; it < 4; ++it) {
                int idx = it * 256 + tid;
                int row = idx >> 3, col = (idx & 7) * 8;
                *(uint4*)&Vs[row][col] =
                    *(const uint4*)(V + ((size_t)b * C2_ + row) * N_ + nt + col);
            }
            __syncthreads();

            f32x4 sc[2][4];
#pragma unroll
            for (int nn = 0; nn < 4; ++nn) {
                f32x4 a0 = (f32x4){0.f, 0.f, 0.f, 0.f};
                f32x4 a1 = (f32x4){0.f, 0.f, 0.f, 0.f};
#pragma unroll
                for (int kk = 0; kk < 4; ++kk) {
                    bf16x8 kf = *(const bf16x8*)&Ks[nn * 16 + l16][kk * 32 + quad * 8];
                    a0 = __builtin_amdgcn_mfma_f32_16x16x32_bf16(qf[0][kk], kf, a0, 0, 0, 0);
                    a1 = __builtin_amdgcn_mfma_f32_16x16x32_bf16(qf[1][kk], kf, a1, 0, 0, 0);
                }
                sc[0][nn] = a0;
                sc[1][nn] = a1;
            }

#pragma unroll
            for (int ms = 0; ms < 2; ++ms)
#pragma unroll
                for (int nn = 0; nn < 4; ++nn)
#pragma unroll
                    for (int r = 0; r < 4; ++r) {
                        float p = __builtin_amdgcn_exp2f(sc[ms][nn][r]);
                        l_r[ms][r] += p;
                        Ps[(ms * 16 + quad * 4 + r) * 72 + nn * 16 + l16] = f2bf(p);
                    }

#pragma unroll
            for (int ks = 0; ks < 2; ++ks) {
                bf16x8 pf0 = *(const bf16x8*)&Ps[(l16) * 72 + ks * 32 + quad * 8];
                bf16x8 pf1 = *(const bf16x8*)&Ps[(16 + l16) * 72 + ks * 32 + quad * 8];
#pragma unroll
                for (int cs = 0; cs < 8; ++cs) {
                    bf16x8 vf = *(const bf16x8*)&Vs[cs * 16 + l16][ks * 32 + quad * 8];
                    o_acc[0][cs] = __builtin_amdgcn_mfma_f32_16x16x32_bf16(pf0, vf, o_acc[0][cs], 0, 0, 0);
                    o_acc[1][cs] = __builtin_amdgcn_mfma_f32_16x16x32_bf16(pf1, vf, o_acc[1][cs], 0, 0, 0);
                }
            }
            __syncthreads();
        }

#pragma unroll
        for (int ms = 0; ms < 2; ++ms)
#pragma unroll
            for (int r = 0; r < 4; ++r) {
                l_r[ms][r] += __shfl_xor(l_r[ms][r], 1);
                l_r[ms][r] += __shfl_xor(l_r[ms][r], 2);
                l_r[ms][r] += __shfl_xor(l_r[ms][r], 4);
                l_r[ms][r] += __shfl_xor(l_r[ms][r], 8);
            }

        if (nsplit > 1) {
#pragma unroll
            for (int ms = 0; ms < 2; ++ms) {
#pragma unroll
                for (int cs = 0; cs < 8; ++cs)
#pragma unroll
                    for (int r = 0; r < 4; ++r) {
                        size_t row = (size_t)s * (B_ * N_) + (size_t)b * N_ +
                                     m0 + wave * 32 + ms * 16 + quad * 4 + r;
                        Opb[row * C2_ + cs * 16 + l16] = f2bf(o_acc[ms][cs][r]);
                    }
                if (l16 == 0)
#pragma unroll
                    for (int r = 0; r < 4; ++r) {
                        size_t row = (size_t)s * (B_ * N_) + (size_t)b * N_ +
                                     m0 + wave * 32 + ms * 16 + quad * 4 + r;
                        lsum[row] = l_r[ms][r];
                    }
            }
        } else {
#pragma unroll
            for (int ms = 0; ms < 2; ++ms)
#pragma unroll
                for (int cs = 0; cs < 8; ++cs)
#pragma unroll
                    for (int r = 0; r < 4; ++r) {
                        float v = o_acc[ms][cs][r] / l_r[ms][r];
                        AO[((size_t)b * N_ + m0 + wave * 32 + ms * 16 + quad * 4 + r) * C2_ +
                           cs * 16 + l16] = f2bf(v);
                    }
        }
    }
    grid_barrier(&bar[1], target);

    // ============== Phase C: split-K combine + outproj + residual ==============
    {
        u16 (*As)[136] = (u16(*)[136])smA;   // [64][136] = 17408 B
        float* Ls = (float*)smC;
        const int per_b = (C_ / 64) * (N_ / 64);    // 256
        const int tiles = B_ * per_b;               // 1024

        for (int t = blockIdx.x; t < tiles; t += gridDim.x) {
            int b   = t / per_b;
            int rem = t % per_b;
            int c0  = (rem / (N_ / 64)) * 64;
            int n0  = (rem % (N_ / 64)) * 64;

            if (nsplit > 1) {
                if (tid < 64) {
                    float L = 0.f;
                    for (int s = 0; s < nsplit; ++s)
                        L += lsum[(size_t)s * (B_ * N_) + (size_t)b * N_ + n0 + tid];
                    Ls[tid] = 1.f / L;
                }
                __syncthreads();
#pragma unroll
                for (int it = 0; it < 4; ++it) {
                    int idx = it * 256 + tid;
                    int n = idx >> 4, c8 = (idx & 15) * 8;
                    float a[8] = {0.f, 0.f, 0.f, 0.f, 0.f, 0.f, 0.f, 0.f};
                    for (int s = 0; s < nsplit; ++s) {
                        const u16* op = Opb +
                            ((size_t)s * (B_ * N_) + (size_t)b * N_ + n0 + n) * C2_ + c8;
                        uint4 raw = *(const uint4*)op;
                        const u16* rp = (const u16*)&raw;
#pragma unroll
                        for (int j = 0; j < 8; ++j) a[j] += bf2f(rp[j]);
                    }
                    float inv = Ls[n];
                    u16 o[8];
#pragma unroll
                    for (int j = 0; j < 8; ++j) o[j] = f2bf(a[j] * inv);
                    *(uint4*)&As[n][c8] = *(const uint4*)o;
                }
            } else {
#pragma unroll
                for (int it = 0; it < 4; ++it) {
                    int idx = it * 256 + tid;
                    int n = idx >> 4, c8 = (idx & 15) * 8;
                    *(uint4*)&As[n][c8] =
                        *(const uint4*)(AO + ((size_t)b * N_ + n0 + n) * C2_ + c8);
                }
            }
            __syncthreads();

            int cw = c0 + wave * 16;
            bf16x8 af[4];
            {
                const float* wrow = w_out + (size_t)(cw + l16) * C2_ + quad * 8;
#pragma unroll
                for (int kk = 0; kk < 4; ++kk) {
                    float w8[8];
                    *(float4*)&w8[0] = *(const float4*)(wrow + kk * 32);
                    *(float4*)&w8[4] = *(const float4*)(wrow + kk * 32 + 4);
                    af[kk] = cvt8(w8);
                }
            }

            f32x4 acc[4];
#pragma unroll
            for (int i = 0; i < 4; ++i) acc[i] = (f32x4){0.f, 0.f, 0.f, 0.f};
#pragma unroll
            for (int nn = 0; nn < 4; ++nn)
#pragma unroll
                for (int kk = 0; kk < 4; ++kk) {
                    bf16x8 bf = *(const bf16x8*)&As[nn * 16 + l16][kk * 32 + quad * 8];
                    acc[nn] = __builtin_amdgcn_mfma_f32_16x16x32_bf16(af[kk], bf, acc[nn], 0, 0, 0);
                }

            float bo[4];
#pragma unroll
            for (int r = 0; r < 4; ++r) bo[r] = b_out[cw + quad * 4 + r];

#pragma unroll
            for (int nn = 0; nn < 4; ++nn)
#pragma unroll
                for (int r = 0; r < 4; ++r) {
                    int c = cw + quad * 4 + r;
                    size_t off = ((size_t)b * C_ + c) * N_ + n0 + nn * 16 + l16;
                    y[off] = x[off] + bo[r] + acc[nn][r];
                }
            __syncthreads();   // As/Ls free for next tile
        }
    }
}

// ---------------------------------------------------------------------------
extern "C" void kernel_launch(void* const* d_in, const int* in_sizes, int n_in,
                              void* d_out, int out_size, void* d_ws, size_t ws_size,
                              hipStream_t stream) {
    const float* x       = (const float*)d_in[0];
    const float* w_theta = (const float*)d_in[1];
    const float* b_theta = (const float*)d_in[2];
    const float* w_phi   = (const float*)d_in[3];
    const float* b_phi   = (const float*)d_in[4];
    const float* w_g     = (const float*)d_in[5];
    const float* b_g     = (const float*)d_in[6];
    const float* w_out   = (const float*)d_in[7];
    const float* b_out   = (const float*)d_in[8];
    float* y = (float*)d_out;

    const size_t SZ = (size_t)B_ * N_ * C2_;        // 2Mi elements
    u16* Q = (u16*)d_ws;
    u16* K = Q + SZ;
    u16* V = K + SZ;
    unsigned* bar = (unsigned*)(V + SZ);             // 256 B barrier region
    char* dyn = (char*)bar + 256;
    size_t fixedB = (size_t)(dyn - (char*)d_ws);     // 12 MiB + 256 B

    size_t perS = SZ * 2 + (size_t)B_ * N_ * 4;      // Opb bf16 + lsum per split

    int S;
    if      (ws_size >= fixedB + 4 * perS) S = 4;    // grid 512 = 2 blocks/CU
    else if (ws_size >= fixedB + 2 * perS) S = 2;    // grid 256
    else                                   S = 1;    // grid 128

    u16*   AO  = (u16*)dyn;       // used only when S == 1
    u16*   Opb = (u16*)dyn;       // aliases AO (AO unused when split)
    float* ls  = (float*)(Opb + (size_t)S * SZ);

    hipMemsetAsync(bar, 0, 256, stream);
    fused_kernel<<<dim3(128 * S), dim3(256), 0, stream>>>(
        x, w_theta, w_phi, w_g, b_theta, b_phi, b_g, w_out, b_out, y,
        Q, K, V, AO, Opb, ls, bar, S);
}

// Round 13
// 154.957 us; speedup vs baseline: 2.6226x; 2.6226x over previous
//
#include <hip/hip_runtime.h>
#include <hip/hip_bf16.h>

#define B_  4
#define C_  256
#define C2_ 128
#define N_  4096
#define LOG2E 1.4426950408889634f

typedef unsigned short u16;
typedef __attribute__((ext_vector_type(8))) short bf16x8;  // 8 bf16 in 4 VGPRs
typedef __attribute__((ext_vector_type(4))) float f32x4;

static __device__ __forceinline__ u16 f2bf(float f) {
    return __builtin_bit_cast(u16, __float2bfloat16(f));
}
static __device__ __forceinline__ float bf2f(u16 u) {
    return __bfloat162float(__builtin_bit_cast(__hip_bfloat16, u));
}
static __device__ __forceinline__ bf16x8 cvt8(const float* p) {
    u16 t[8];
#pragma unroll
    for (int j = 0; j < 8; ++j) t[j] = f2bf(p[j]);
    return *(const bf16x8*)t;
}

// ---------------------------------------------------------------------------
// Kernel 1 (projx): fused x-transpose + 3-way MFMA projection.
// Key change vs r10: weights are staged fp32->bf16 into LDS with COALESCED
// cooperative loads (16 float4/thread per stage, fully pipelined), then MFMA
// B-frags come from LDS — removes the ~96 dependent 200-cyc L2 loads/wave
// that made the direct-read version latency-bound.
// Block = (b, 64-n tile) = 256 blocks, 256 thr, 4 waves x 16 n-rows.
// LDS: XTs 33792 + Ws 33792 = 67584 B -> 2 blocks/CU.
// ---------------------------------------------------------------------------
__global__ __launch_bounds__(256, 2) void projx_kernel(
    const float* __restrict__ x,
    const float* __restrict__ wt, const float* __restrict__ wp,
    const float* __restrict__ wg,
    const float* __restrict__ b_theta, const float* __restrict__ b_phi,
    const float* __restrict__ b_g,
    u16* __restrict__ Q, u16* __restrict__ K, u16* __restrict__ V) {
    __shared__ __align__(16) u16 XTs[64][264];   // 33792 B; Vt overlays later
    __shared__ __align__(16) u16 Ws[64][264];    // 33792 B (weight half-tile)
    u16 (*Vt)[72] = (u16(*)[72])XTs;             // [128][72] = 18432 B

    int bid = blockIdx.x;
    int b   = bid / (N_ / 64);
    int n0  = (bid % (N_ / 64)) * 64;
    int tid = threadIdx.x;
    int wave = tid >> 6, lane = tid & 63, quad = (lane >> 4) & 3, l16 = lane & 15;

    // ---- stage + transpose x tile [256 c][64 n] fp32 -> XTs[n][c] bf16 ----
    // items: c-pair p (0..127) x n-quad q (0..15) = 2048, 8 iters
#pragma unroll
    for (int it = 0; it < 8; ++it) {
        int idx = it * 256 + tid;
        int q = idx & 15, p = idx >> 4;
        const float* r0 = x + ((size_t)b * C_ + 2 * p) * N_ + n0 + 4 * q;
        float4 v0 = *(const float4*)r0;
        float4 v1 = *(const float4*)(r0 + N_);
        const float* f0 = (const float*)&v0;
        const float* f1 = (const float*)&v1;
#pragma unroll
        for (int j = 0; j < 4; ++j) {
            unsigned pk = (unsigned)f2bf(f0[j]) | ((unsigned)f2bf(f1[j]) << 16);
            *(unsigned*)&XTs[4 * q + j][2 * p] = pk;
        }
    }
    __syncthreads();

    // A fragments: wave's 16 n-rows, resident whole kernel
    bf16x8 af[8];
#pragma unroll
    for (int ks = 0; ks < 8; ++ks)
        af[ks] = *(const bf16x8*)&XTs[wave * 16 + l16][ks * 32 + quad * 8];
    __syncthreads();   // XTs consumed -> Vt may overlay

    const float* wms[3]    = { wt, wp, wg };
    const float* biases[3] = { b_theta, b_phi, b_g };

#pragma unroll
    for (int mat = 0; mat < 3; ++mat) {
        const float* wm = wms[mat];
        const float* bias = biases[mat];
#pragma unroll
        for (int h = 0; h < 2; ++h) {
            // ---- stage weight half [64 c2][256 c] fp32 -> Ws bf16 ----
#pragma unroll
            for (int it = 0; it < 8; ++it) {
                int idx = it * 256 + tid;
                int row = idx >> 5, c8 = (idx & 31) * 8;
                const float* src = wm + (size_t)(h * 64 + row) * C_ + c8;
                float w8[8];
                *(float4*)&w8[0] = *(const float4*)src;
                *(float4*)&w8[4] = *(const float4*)(src + 4);
                bf16x8 v = cvt8(w8);
                *(bf16x8*)&Ws[row][c8] = v;
            }
            __syncthreads();

            f32x4 acc[4];
#pragma unroll
            for (int i = 0; i < 4; ++i) acc[i] = (f32x4){0.f, 0.f, 0.f, 0.f};
#pragma unroll
            for (int ct = 0; ct < 4; ++ct)
#pragma unroll
                for (int ks = 0; ks < 8; ++ks) {
                    bf16x8 bf = *(const bf16x8*)&Ws[ct * 16 + l16][ks * 32 + quad * 8];
                    acc[ct] = __builtin_amdgcn_mfma_f32_16x16x32_bf16(
                        af[ks], bf, acc[ct], 0, 0, 0);
                }

            if (mat < 2) {
                u16* dst = mat == 0 ? Q : K;
                float sc = mat == 0 ? LOG2E : 1.0f;
#pragma unroll
                for (int ct = 0; ct < 4; ++ct) {
                    int c2 = h * 64 + ct * 16 + l16;
                    float bb = bias[c2];
#pragma unroll
                    for (int r = 0; r < 4; ++r) {
                        int n = n0 + wave * 16 + quad * 4 + r;
                        dst[((size_t)b * N_ + n) * C2_ + c2] =
                            f2bf((acc[ct][r] + bb) * sc);
                    }
                }
            } else {
#pragma unroll
                for (int ct = 0; ct < 4; ++ct) {
                    int c2 = h * 64 + ct * 16 + l16;
                    float bb = bias[c2];
#pragma unroll
                    for (int r = 0; r < 4; ++r)
                        Vt[c2][wave * 16 + quad * 4 + r] = f2bf(acc[ct][r] + bb);
                }
            }
            __syncthreads();   // Ws free for restaging
        }
    }

    // cooperative V[b][c2][n0..n0+63] write: 128 rows x 8 uint4
#pragma unroll
    for (int it = 0; it < 4; ++it) {
        int idx = it * 256 + tid;
        int row = idx >> 3, n8 = (idx & 7) * 8;
        *(uint4*)(V + ((size_t)b * C2_ + row) * N_ + n0 + n8) =
            *(const uint4*)&Vt[row][n8];
    }
}

// ---------------------------------------------------------------------------
// Kernel 2: flash attention — r8-proven body (56-58us), BM=128, bf16
// partials, uneven-split capable. Launched at S=4 (proven best).
// ---------------------------------------------------------------------------
__global__ __launch_bounds__(256, 2) void attn_kernel(
    const u16* __restrict__ Q, const u16* __restrict__ K,
    const u16* __restrict__ V, u16* __restrict__ AO,
    u16* __restrict__ Opb, float* __restrict__ lsum, int nsplit) {
    const int BM = 128, BN = 64, D = C2_;
    const int per = B_ * (N_ / BM);      // 128
    int s    = blockIdx.x / per;
    int r0   = blockIdx.x % per;
    int b    = r0 / (N_ / BM);
    int m0   = (r0 % (N_ / BM)) * BM;
    int tid  = threadIdx.x;
    int wave = tid >> 6, lane = tid & 63, quad = (lane >> 4) & 3, l16 = lane & 15;

    __shared__ __align__(16) u16 Ks[BN][D + 8];        // 17408 B
    __shared__ __align__(16) u16 Vs[D][BN + 8];        // 18432 B
    __shared__ __align__(16) u16 Psb[4][32][BN + 8];   // 18432 B
    u16* Ps = &Psb[wave][0][0];

    bf16x8 qf[2][4];
#pragma unroll
    for (int ms = 0; ms < 2; ++ms) {
        const u16* qp = Q + ((size_t)b * N_ + m0 + wave * 32 + ms * 16 + l16) * D;
#pragma unroll
        for (int kk = 0; kk < 4; ++kk)
            qf[ms][kk] = *(const bf16x8*)(qp + kk * 32 + quad * 8);
    }

    float l_r[2][4] = {{0.f, 0.f, 0.f, 0.f}, {0.f, 0.f, 0.f, 0.f}};
    f32x4 o_acc[2][8];
#pragma unroll
    for (int ms = 0; ms < 2; ++ms)
#pragma unroll
        for (int i = 0; i < 8; ++i) o_acc[ms][i] = (f32x4){0.f, 0.f, 0.f, 0.f};

    const int tiles = N_ / BN;                 // 64
    const int base = tiles / nsplit, rem = tiles % nsplit;
    const int t0 = s * base + (s < rem ? s : rem);
    const int cnt = base + (s < rem ? 1 : 0);
    const int nt0 = t0 * BN, nt1 = (t0 + cnt) * BN;

    for (int nt = nt0; nt < nt1; nt += BN) {
        const u16* kp = K + ((size_t)b * N_ + nt) * D;
#pragma unroll
        for (int it = 0; it < 4; ++it) {
            int idx = it * 256 + tid;
            int row = idx >> 4, col = (idx & 15) * 8;
            *(uint4*)&Ks[row][col] = *(const uint4*)(kp + row * D + col);
        }
#pragma unroll
        for (int it = 0; it < 4; ++it) {
            int idx = it * 256 + tid;
            int row = idx >> 3, col = (idx & 7) * 8;
            *(uint4*)&Vs[row][col] =
                *(const uint4*)(V + ((size_t)b * C2_ + row) * N_ + nt + col);
        }
        __syncthreads();

        f32x4 sc[2][4];
#pragma unroll
        for (int nn = 0; nn < 4; ++nn) {
            f32x4 a0 = (f32x4){0.f, 0.f, 0.f, 0.f};
            f32x4 a1 = (f32x4){0.f, 0.f, 0.f, 0.f};
#pragma unroll
            for (int kk = 0; kk < 4; ++kk) {
                bf16x8 kf = *(const bf16x8*)&Ks[nn * 16 + l16][kk * 32 + quad * 8];
                a0 = __builtin_amdgcn_mfma_f32_16x16x32_bf16(qf[0][kk], kf, a0, 0, 0, 0);
                a1 = __builtin_amdgcn_mfma_f32_16x16x32_bf16(qf[1][kk], kf, a1, 0, 0, 0);
            }
            sc[0][nn] = a0;
            sc[1][nn] = a1;
        }

#pragma unroll
        for (int ms = 0; ms < 2; ++ms)
#pragma unroll
            for (int nn = 0; nn < 4; ++nn)
#pragma unroll
                for (int r = 0; r < 4; ++r) {
                    float p = __builtin_amdgcn_exp2f(sc[ms][nn][r]);
                    l_r[ms][r] += p;
                    Ps[(ms * 16 + quad * 4 + r) * (BN + 8) + nn * 16 + l16] = f2bf(p);
                }

#pragma unroll
        for (int ks = 0; ks < 2; ++ks) {
            bf16x8 pf0 = *(const bf16x8*)&Ps[(l16) * (BN + 8) + ks * 32 + quad * 8];
            bf16x8 pf1 = *(const bf16x8*)&Ps[(16 + l16) * (BN + 8) + ks * 32 + quad * 8];
#pragma unroll
            for (int cs = 0; cs < 8; ++cs) {
                bf16x8 vf = *(const bf16x8*)&Vs[cs * 16 + l16][ks * 32 + quad * 8];
                o_acc[0][cs] = __builtin_amdgcn_mfma_f32_16x16x32_bf16(pf0, vf, o_acc[0][cs], 0, 0, 0);
                o_acc[1][cs] = __builtin_amdgcn_mfma_f32_16x16x32_bf16(pf1, vf, o_acc[1][cs], 0, 0, 0);
            }
        }
        __syncthreads();
    }

#pragma unroll
    for (int ms = 0; ms < 2; ++ms)
#pragma unroll
        for (int r = 0; r < 4; ++r) {
            l_r[ms][r] += __shfl_xor(l_r[ms][r], 1);
            l_r[ms][r] += __shfl_xor(l_r[ms][r], 2);
            l_r[ms][r] += __shfl_xor(l_r[ms][r], 4);
            l_r[ms][r] += __shfl_xor(l_r[ms][r], 8);
        }

    if (Opb) {
#pragma unroll
        for (int ms = 0; ms < 2; ++ms) {
#pragma unroll
            for (int cs = 0; cs < 8; ++cs)
#pragma unroll
                for (int r = 0; r < 4; ++r) {
                    size_t row = (size_t)s * (B_ * N_) + (size_t)b * N_ +
                                 m0 + wave * 32 + ms * 16 + quad * 4 + r;
                    Opb[row * C2_ + cs * 16 + l16] = f2bf(o_acc[ms][cs][r]);
                }
            if (l16 == 0)
#pragma unroll
                for (int r = 0; r < 4; ++r) {
                    size_t row = (size_t)s * (B_ * N_) + (size_t)b * N_ +
                                 m0 + wave * 32 + ms * 16 + quad * 4 + r;
                    lsum[row] = l_r[ms][r];
                }
        }
    } else {
#pragma unroll
        for (int ms = 0; ms < 2; ++ms)
#pragma unroll
            for (int cs = 0; cs < 8; ++cs)
#pragma unroll
                for (int r = 0; r < 4; ++r) {
                    float v = o_acc[ms][cs][r] / l_r[ms][r];
                    AO[((size_t)b * N_ + m0 + wave * 32 + ms * 16 + quad * 4 + r) * C2_ +
                       cs * 16 + l16] = f2bf(v);
                }
    }
}

// ---------------------------------------------------------------------------
// Kernel 3: outproj with fused split-K combine.
// Key change vs r10: w_out tile staged fp32->bf16 into LDS with coalesced
// loads; A-frags then read from LDS (was: 16 scattered global loads/thread).
// LDS: As 17408 + Ws2 17408 + Ls 256 -> ~35 KB -> 4 blocks/CU.
// ---------------------------------------------------------------------------
__global__ __launch_bounds__(256) void outproj_kernel(
    const float* __restrict__ x, const u16* __restrict__ Opb,
    const float* __restrict__ lsum, const u16* __restrict__ AO,
    const float* __restrict__ w_out, const float* __restrict__ b_out,
    float* __restrict__ y, int nsplit) {
    __shared__ __align__(16) u16 As[64][C2_ + 8];    // 17408 B
    __shared__ __align__(16) u16 Ws2[64][C2_ + 8];   // 17408 B
    __shared__ float Ls[64];
    int bid = blockIdx.x;
    int per_b = (C_ / 64) * (N_ / 64);   // 256
    int b   = bid / per_b;
    int rem = bid % per_b;
    int c0  = (rem / (N_ / 64)) * 64;
    int n0  = (rem % (N_ / 64)) * 64;
    int tid = threadIdx.x;
    int wave = tid >> 6, lane = tid & 63, quad = (lane >> 4) & 3, l16 = lane & 15;

    // ---- stage w_out tile [64 c][128 c2] fp32 -> Ws2 bf16 (coalesced) ----
#pragma unroll
    for (int it = 0; it < 4; ++it) {
        int idx = it * 256 + tid;
        int row = idx >> 4, c8 = (idx & 15) * 8;
        const float* src = w_out + (size_t)(c0 + row) * C2_ + c8;
        float w8[8];
        *(float4*)&w8[0] = *(const float4*)src;
        *(float4*)&w8[4] = *(const float4*)(src + 4);
        bf16x8 v = cvt8(w8);
        *(bf16x8*)&Ws2[row][c8] = v;
    }

    if (nsplit > 1) {   // grid-uniform branch
        if (tid < 64) {
            float L = 0.f;
            for (int s = 0; s < nsplit; ++s)
                L += lsum[(size_t)s * (B_ * N_) + (size_t)b * N_ + n0 + tid];
            Ls[tid] = 1.f / L;
        }
        __syncthreads();
#pragma unroll
        for (int it = 0; it < 4; ++it) {
            int idx = it * 256 + tid;
            int n = idx >> 4, c8 = (idx & 15) * 8;
            float a[8] = {0.f, 0.f, 0.f, 0.f, 0.f, 0.f, 0.f, 0.f};
            for (int s = 0; s < nsplit; ++s) {
                const u16* op = Opb +
                    ((size_t)s * (B_ * N_) + (size_t)b * N_ + n0 + n) * C2_ + c8;
                uint4 raw = *(const uint4*)op;
                const u16* rp = (const u16*)&raw;
#pragma unroll
                for (int j = 0; j < 8; ++j) a[j] += bf2f(rp[j]);
            }
            float inv = Ls[n];
            u16 o[8];
#pragma unroll
            for (int j = 0; j < 8; ++j) o[j] = f2bf(a[j] * inv);
            *(uint4*)&As[n][c8] = *(const uint4*)o;
        }
    } else {
#pragma unroll
        for (int it = 0; it < 4; ++it) {
            int idx = it * 256 + tid;
            int n = idx >> 4, c8 = (idx & 15) * 8;
            *(uint4*)&As[n][c8] =
                *(const uint4*)(AO + ((size_t)b * N_ + n0 + n) * C2_ + c8);
        }
    }
    __syncthreads();

    // A-frags from LDS-staged w_out
    bf16x8 af[4];
#pragma unroll
    for (int kk = 0; kk < 4; ++kk)
        af[kk] = *(const bf16x8*)&Ws2[wave * 16 + l16][kk * 32 + quad * 8];

    f32x4 acc[4];
#pragma unroll
    for (int i = 0; i < 4; ++i) acc[i] = (f32x4){0.f, 0.f, 0.f, 0.f};

#pragma unroll
    for (int nn = 0; nn < 4; ++nn)
#pragma unroll
        for (int kk = 0; kk < 4; ++kk) {
            bf16x8 bf = *(const bf16x8*)&As[nn * 16 + l16][kk * 32 + quad * 8];
            acc[nn] = __builtin_amdgcn_mfma_f32_16x16x32_bf16(af[kk], bf, acc[nn], 0, 0, 0);
        }

    int cw = c0 + wave * 16;
    float bo[4];
#pragma unroll
    for (int r = 0; r < 4; ++r) bo[r] = b_out[cw + quad * 4 + r];

#pragma unroll
    for (int nn = 0; nn < 4; ++nn)
#pragma unroll
        for (int r = 0; r < 4; ++r) {
            int c = cw + quad * 4 + r;
            size_t off = ((size_t)b * C_ + c) * N_ + n0 + nn * 16 + l16;
            y[off] = x[off] + bo[r] + acc[nn][r];
        }
}

// ---------------------------------------------------------------------------
extern "C" void kernel_launch(void* const* d_in, const int* in_sizes, int n_in,
                              void* d_out, int out_size, void* d_ws, size_t ws_size,
                              hipStream_t stream) {
    const float* x       = (const float*)d_in[0];
    const float* w_theta = (const float*)d_in[1];
    const float* b_theta = (const float*)d_in[2];
    const float* w_phi   = (const float*)d_in[3];
    const float* b_phi   = (const float*)d_in[4];
    const float* w_g     = (const float*)d_in[5];
    const float* b_g     = (const float*)d_in[6];
    const float* w_out   = (const float*)d_in[7];
    const float* b_out   = (const float*)d_in[8];
    float* y = (float*)d_out;

    const size_t SZ = (size_t)B_ * N_ * C2_;        // 2Mi elements
    u16* Q = (u16*)d_ws;
    u16* K = Q + SZ;
    u16* V = K + SZ;
    char* dyn = (char*)(V + SZ);
    size_t fixedB = 3 * SZ * 2;                      // 12 MiB

    size_t perS = SZ * 2 + (size_t)B_ * N_ * 4;      // Opb bf16 + lsum per split

    int S;
    if      (ws_size >= fixedB + 4 * perS) S = 4;    // grid 512 (proven best)
    else if (ws_size >= fixedB + 2 * perS) S = 2;
    else                                   S = 1;

    u16*   AO  = (u16*)dyn;       // used only when S == 1
    u16*   Opb = nullptr;
    float* ls  = nullptr;
    if (S > 1) {
        Opb = (u16*)dyn;          // aliases AO (AO unused when split)
        ls  = (float*)(Opb + (size_t)S * SZ);
    }

    projx_kernel<<<B_ * (N_ / 64), 256, 0, stream>>>(
        x, w_theta, w_phi, w_g, b_theta, b_phi, b_g, Q, K, V);
    attn_kernel<<<B_ * (N_ / 128) * S, 256, 0, stream>>>(Q, K, V, AO, Opb, ls, S);
    outproj_kernel<<<B_ * (C_ / 64) * (N_ / 64), 256, 0, stream>>>(
        x, Opb, ls, AO, w_out, b_out, y, S);
}